// Round 8
// baseline (219.558 us; speedup 1.0000x reference)
//
#include <hip/hip_runtime.h>

typedef _Float16 f16;
typedef _Float16 f16x2 __attribute__((ext_vector_type(2)));
typedef _Float16 f16x4 __attribute__((ext_vector_type(4)));
typedef _Float16 f16x8 __attribute__((ext_vector_type(8)));
typedef float f32x4 __attribute__((ext_vector_type(4)));
typedef float f32x16 __attribute__((ext_vector_type(16)));

#define MFMA16(a, b, c) __builtin_amdgcn_mfma_f32_16x16x32_f16((a), (b), (c), 0, 0, 0)
#define MFMA32(a, b, c) __builtin_amdgcn_mfma_f32_32x32x16_f16((a), (b), (c), 0, 0, 0)

// ---------------- fp32 -> f16 convert ----------------
__global__ void cvt_f32_f16(const float* __restrict__ s, f16* __restrict__ d, int n) {
    int i = (blockIdx.x * 256 + threadIdx.x) * 4;
    if (i < n) {
        float4 v = *(const float4*)(s + i);
        f16x4 o = {(f16)v.x, (f16)v.y, (f16)v.z, (f16)v.w};
        *(f16x4*)(d + i) = o;
    }
}

// ---------------- NT GEMM: C[m][n] = sum_k A[m][k] * W[n][k] (+bias epilogues) ----
// Software-pipelined staging: next k-step's A/B global loads issued right after
// barrier 1 (T14 issue-early / write-late), hidden under the MFMA phase.
// MODE 0 epilogue packs K and V into MFMA-fragment-major layouts:
//   Kp[b][kb=s>>5][kc=d>>4][lane=(d>>3&1)*32+(s&31)][e=d&7]
//   Vp[b][db=d>>5][kw=s>>4][lane=(s>>3&1)*32+(d&31)][e=s&7]
template<int MODE>
__global__ __launch_bounds__(256) void gemm_nt(const f16* __restrict__ A, const f16* __restrict__ W,
                                               const float* __restrict__ bias, float* __restrict__ Cf,
                                               f16* __restrict__ Qb, f16* __restrict__ Kb,
                                               f16* __restrict__ Vt) {
    __shared__ f16 As[64][40];
    __shared__ f16 Bs[64][40];
    const int m0 = blockIdx.x * 64, n0 = blockIdx.y * 64;
    const int tid = threadIdx.x;
    const int w = tid >> 6, l = tid & 63;
    const int wm = w >> 1, wn = w & 1;
    const int lr = l & 15, lg = l >> 4;
    const int srow = tid >> 2, scol = (tid & 3) * 8;
    const f16* ag = A + (size_t)(m0 + srow) * 512 + scol;
    const f16* bg = W + (size_t)(n0 + srow) * 512 + scol;
    f32x4 acc[2][2] = {};
    f16x8 ar = *(const f16x8*)ag;
    f16x8 br = *(const f16x8*)bg;
    for (int k0 = 0; k0 < 512; k0 += 32) {
        *(f16x8*)&As[srow][scol] = ar;
        *(f16x8*)&Bs[srow][scol] = br;
        __syncthreads();
        if (k0 + 32 < 512) {
            ar = *(const f16x8*)(ag + k0 + 32);
            br = *(const f16x8*)(bg + k0 + 32);
        }
        f16x8 af[2], bf[2];
#pragma unroll
        for (int mf = 0; mf < 2; ++mf) af[mf] = *(f16x8*)&As[32 * wm + 16 * mf + lr][8 * lg];
#pragma unroll
        for (int nf = 0; nf < 2; ++nf) bf[nf] = *(f16x8*)&Bs[32 * wn + 16 * nf + lr][8 * lg];
#pragma unroll
        for (int mf = 0; mf < 2; ++mf)
#pragma unroll
            for (int nf = 0; nf < 2; ++nf) acc[mf][nf] = MFMA16(af[mf], bf[nf], acc[mf][nf]);
        __syncthreads();
    }
#pragma unroll
    for (int mf = 0; mf < 2; ++mf)
#pragma unroll
        for (int nf = 0; nf < 2; ++nf)
#pragma unroll
            for (int r = 0; r < 4; ++r) {
                int rr = 32 * wm + 16 * mf + 4 * lg + r;
                int cc = 32 * wn + 16 * nf + lr;
                int m = m0 + rr, e = n0 + cc;
                float val = acc[mf][nf][r] + bias[e];
                if (MODE == 0) {
                    int bb = m >> 11, s = m & 2047;
                    if (e < 512) {
                        Qb[((size_t)bb * 2048 + s) * 512 + e] = (f16)(val * 0.04419417382415922f);
                    } else if (e < 1024) {
                        int d = e - 512;
                        Kb[((((size_t)bb * 64 + (s >> 5)) * 32 + (d >> 4)) * 64
                            + ((d >> 3) & 1) * 32 + (s & 31)) * 8 + (d & 7)] = (f16)val;
                    } else {
                        int d = e - 1024;
                        Vt[((((size_t)bb * 16 + (d >> 5)) * 128 + (s >> 4)) * 64
                            + ((s >> 3) & 1) * 32 + (d & 31)) * 8 + (s & 7)] = (f16)val;
                    }
                } else {
                    Cf[(size_t)m * 512 + e] = val;
                }
            }
}

// ---------------- flash attention: 8 waves, QBLK=32, KEYTILE=256, 32x32 MFMA ----
// Batched register prefetch: all 32 K-frag + 32 V-frag loads issued at kt top
// (64 independent lane-contiguous loads in flight per wave -> latency exposed
// ~once per kt, V hidden under QK^T+softmax). Explicit unrolled reg arrays.
template<int NSPLIT, bool PART>
__global__ __launch_bounds__(512, 4) void flash_attn(const f16* __restrict__ Qb, const f16* __restrict__ Kb,
                                                     const f16* __restrict__ Vt, f16* __restrict__ AO,
                                                     f16* __restrict__ Opart, float* __restrict__ Ml) {
    __shared__ f16 Qs[32 * 512];   // [row][chunk^(row&7)] on 16B chunks
    __shared__ f16 P_lds[32 * 256];
    __shared__ float mbuf[32][8];
    __shared__ float lbuf[32][8];
    __shared__ float abuf[32];

    const int bid = blockIdx.x;
    const int xcd = bid & 7, slot = bid >> 3;
    const int b = xcd >> 1;
    const int t = slot * 2 + (xcd & 1);      // 0 .. 64*NSPLIT-1
    const int q0 = (t / NSPLIT) * 32;
    const int ks = t % NSPLIT;
    const int SPLITLEN = 2048 / NSPLIT;
    const int nkt = SPLITLEN / 256;

    const int tid = threadIdx.x;
    const int j = tid >> 6, l = tid & 63;
    const int q = l & 31, lh = l >> 5;

    const f16* Qg = Qb + ((size_t)b * 2048 + q0) * 512;
    const f16* Kg = Kb + ((size_t)b * 64 + (size_t)ks * (SPLITLEN / 32)) * 32 * 512;
    const f16* Vg = Vt + (size_t)b * 16 * 128 * 512 + (size_t)(ks * (SPLITLEN / 16)) * 512;

    // stage Q tile [32][512] into swizzled LDS (coalesced 16B per lane)
    for (int i = tid; i < 2048; i += 512) {
        int r = i >> 6, ch = i & 63;
        *(f16x8*)&Qs[r * 512 + ((ch ^ (r & 7)) * 8)] = *(const f16x8*)&Qg[(size_t)r * 512 + ch * 8];
    }

    f32x16 o[2] = {};
    float m_st = -1e30f, l_st = 0.f;
    char* Pq = (char*)&P_lds[0];
    const uint swz = ((uint)(q & 15)) << 4;
    const int qbase = q * 512, qx = q & 7;
    __syncthreads();

    for (int kt = 0; kt < nkt; ++kt) {
        const int key0 = kt * 256;
        // ---- batch-issue all K and V fragment loads for this kt ----
        const f16* kp = Kg + ((size_t)((key0 >> 5) + j) * 32) * 512 + (size_t)l * 8;
        const f16* vpb = Vg + ((size_t)(2 * j) * 128 + (key0 >> 4)) * 512 + (size_t)l * 8;
        f16x8 kreg[32], vreg[32];
#pragma unroll
        for (int i = 0; i < 32; ++i) kreg[i] = *(const f16x8*)(kp + (size_t)i * 512);
#pragma unroll
        for (int i = 0; i < 32; ++i)
            vreg[i] = *(const f16x8*)(vpb + (size_t)((i >> 4) * 128 + (i & 15)) * 512);
        // ---- QK^T (swapped): S^T[32 keys j-slice][32 q]; Q frags from LDS ----
        f32x16 sA = {}, sB = {};
#pragma unroll
        for (int kc = 0; kc < 32; kc += 2) {
            f16x8 q0f = *(f16x8*)&Qs[qbase + (((2 * kc + lh) ^ qx) * 8)];
            f16x8 q1f = *(f16x8*)&Qs[qbase + (((2 * kc + 2 + lh) ^ qx) * 8)];
            sA = MFMA32(kreg[kc], q0f, sA);
            sB = MFMA32(kreg[kc + 1], q1f, sB);
        }
        float s[16];
#pragma unroll
        for (int r = 0; r < 16; ++r) s[r] = sA[r] + sB[r];
        // ---- in-register partial max over own 32 keys ----
        float mt = s[0];
#pragma unroll
        for (int r = 1; r < 16; ++r) mt = fmaxf(mt, s[r]);
        mt = fmaxf(mt, __shfl_xor(mt, 32));
        if (l < 32) mbuf[q][j] = mt;
        __syncthreads();  // barrier 1
        float mnew = m_st;
        {
            float4 mv0 = *(float4*)&mbuf[q][0];
            float4 mv1 = *(float4*)&mbuf[q][4];
            mnew = fmaxf(mnew, fmaxf(fmaxf(mv0.x, mv0.y), fmaxf(mv0.z, mv0.w)));
            mnew = fmaxf(mnew, fmaxf(fmaxf(mv1.x, mv1.y), fmaxf(mv1.z, mv1.w)));
        }
        float alpha = __expf(m_st - mnew);
        if (l < 32) abuf[q] = alpha;
        float ps = 0.f;
#pragma unroll
        for (int r = 0; r < 16; ++r) {
            s[r] = __expf(s[r] - mnew);
            ps += s[r];
        }
        ps += __shfl_xor(ps, 32);
        if (l < 32) lbuf[q][j] = ps;
        // pack P -> P_lds[q][key], XOR-swizzled, f16x4 chunks (keys e+8i+4lh+32j)
        {
            const uint rowb = (uint)q * 512;
#pragma unroll
            for (int i = 0; i < 4; ++i) {
                int key = 8 * i + 4 * lh + 32 * j;
                f16x4 pk = {(f16)s[4 * i], (f16)s[4 * i + 1], (f16)s[4 * i + 2], (f16)s[4 * i + 3]};
                *(f16x4*)(Pq + ((rowb + (uint)key * 2) ^ swz)) = pk;
            }
        }
        m_st = mnew;
        __syncthreads();  // barrier 2
        // ---- combine l across 8 j-waves ----
        {
            float4 lv0 = *(float4*)&lbuf[q][0];
            float4 lv1 = *(float4*)&lbuf[q][4];
            l_st = l_st * alpha + ((lv0.x + lv0.y) + (lv0.z + lv0.w))
                                + ((lv1.x + lv1.y) + (lv1.z + lv1.w));
        }
        // ---- rescale O: alpha per O-reg's q-row via abuf broadcast ----
        float av[4][4];
#pragma unroll
        for (int g = 0; g < 4; ++g) {
            float4 a4 = *(float4*)&abuf[8 * g + 4 * lh];
            av[g][0] = a4.x; av[g][1] = a4.y; av[g][2] = a4.z; av[g][3] = a4.w;
        }
#pragma unroll
        for (int dt = 0; dt < 2; ++dt)
#pragma unroll
            for (int r = 0; r < 16; ++r) o[dt][r] *= av[r >> 2][r & 3];
        // ---- PV: O[32q][64d j-slice] += P[32q][256k] * V (V already in regs) ----
#pragma unroll
        for (int kk = 0; kk < 16; ++kk) {
            f16x8 paf = *(f16x8*)(Pq + (((uint)q * 512 + (uint)(16 * kk + 8 * lh) * 2) ^ swz));
            o[0] = MFMA32(paf, vreg[kk], o[0]);
            o[1] = MFMA32(paf, vreg[16 + kk], o[1]);
        }
    }
    __syncthreads();  // protect abuf reuse below against stragglers in PV
    if (l < 32) abuf[q] = l_st;
    if (PART && l < 32 && j == 0) {
        Ml[((size_t)bid * 32 + q) * 2 + 0] = m_st;
        Ml[((size_t)bid * 32 + q) * 2 + 1] = l_st;
    }
    __syncthreads();
    float iv[4][4];
#pragma unroll
    for (int g = 0; g < 4; ++g) {
        float4 a4 = *(float4*)&abuf[8 * g + 4 * lh];
        iv[g][0] = 1.f / a4.x; iv[g][1] = 1.f / a4.y; iv[g][2] = 1.f / a4.z; iv[g][3] = 1.f / a4.w;
    }
    f16* op = PART ? (Opart + (size_t)bid * 32 * 512 + 64 * j)
                   : (AO + ((size_t)(b * 2048 + q0)) * 512 + 64 * j);
#pragma unroll
    for (int r = 0; r < 16; ++r) {
        int qr = (r & 3) + 8 * (r >> 2) + 4 * lh;
        float inv = iv[r >> 2][r & 3];
#pragma unroll
        for (int dt = 0; dt < 2; ++dt)
            op[(size_t)qr * 512 + 32 * dt + q] = (f16)(o[dt][r] * inv);
    }
}

// ---------------- split-K combine (NS partials per 32-row q-block) ----------------
template<int NS>
__global__ __launch_bounds__(256) void combineN(const f16* __restrict__ Opart, const float* __restrict__ Ml,
                                                f16* __restrict__ AO) {
    int gid = blockIdx.x * 256 + threadIdx.x;
    int row = gid >> 6, col0 = (gid & 63) * 8;
    int b = row >> 11, qq = row & 2047;
    int qb = qq >> 5, qr = qq & 31;
    int bids[NS];
    float m[NS], ll[NS];
#pragma unroll
    for (int s = 0; s < NS; ++s) {
        int t = qb * NS + s;
        bids[s] = (t >> 1) * 8 + 2 * b + (t & 1);
        m[s] = Ml[((size_t)bids[s] * 32 + qr) * 2];
        ll[s] = Ml[((size_t)bids[s] * 32 + qr) * 2 + 1];
    }
    float M = m[0];
#pragma unroll
    for (int s = 1; s < NS; ++s) M = fmaxf(M, m[s]);
    float c[NS], W = 0.f;
#pragma unroll
    for (int s = 0; s < NS; ++s) {
        c[s] = __expf(m[s] - M) * ll[s];
        W += c[s];
    }
    float invW = 1.f / W;
    float av[8] = {};
#pragma unroll
    for (int s = 0; s < NS; ++s) {
        f16x8 v = *(const f16x8*)&Opart[((size_t)bids[s] * 32 + qr) * 512 + col0];
        float cs = c[s] * invW;
#pragma unroll
        for (int jj = 0; jj < 8; ++jj) av[jj] += cs * (float)v[jj];
    }
    f16x8 o8;
#pragma unroll
    for (int jj = 0; jj < 8; ++jj) o8[jj] = (f16)av[jj];
    *(f16x8*)&AO[(size_t)row * 512 + col0] = o8;
}

// ---------------- launch ----------------
extern "C" void kernel_launch(void* const* d_in, const int* in_sizes, int n_in,
                              void* d_out, int out_size, void* d_ws, size_t ws_size,
                              hipStream_t stream) {
    (void)in_sizes; (void)n_in; (void)out_size;
    const float* x = (const float*)d_in[0];
    const float* qkv_w = (const float*)d_in[1];
    const float* qkv_b = (const float*)d_in[2];
    const float* out_w = (const float*)d_in[3];
    const float* out_b = (const float*)d_in[4];
    char* ws = (char*)d_ws;
    f16* xh    = (f16*)(ws + 0);
    f16* wqkvh = (f16*)(ws + 8388608);
    f16* wouth = (f16*)(ws + 9961472);
    f16* Qb    = (f16*)(ws + 10485760);
    f16* Kb    = (f16*)(ws + 18874368);  // packed K fragments, 8,388,608
    f16* Vt    = (f16*)(ws + 27262976);  // packed V fragments, 8,388,608
    f16* AO    = (f16*)(ws + 35651584);
    f16* Opart = (f16*)(ws + 44040192);               // 512*32*512*2 = 16,777,216
    float* Ml  = (float*)(ws + 44040192 + 16777216);  // 512*32*2*4 = 131,072
    const size_t NEED = 44040192ull + 16777216ull + 131072ull;

    cvt_f32_f16<<<4096, 256, 0, stream>>>(x, xh, 4194304);
    cvt_f32_f16<<<768, 256, 0, stream>>>(qkv_w, wqkvh, 786432);
    cvt_f32_f16<<<256, 256, 0, stream>>>(out_w, wouth, 262144);

    gemm_nt<0><<<dim3(128, 24), 256, 0, stream>>>(xh, wqkvh, qkv_b, nullptr, Qb, Kb, Vt);

    if (ws_size >= NEED) {
        flash_attn<2, true><<<512, 512, 0, stream>>>(Qb, Kb, Vt, nullptr, Opart, Ml);
        combineN<2><<<2048, 256, 0, stream>>>(Opart, Ml, AO);
    } else {
        flash_attn<1, false><<<256, 512, 0, stream>>>(Qb, Kb, Vt, AO, nullptr, nullptr);
    }

    gemm_nt<1><<<dim3(128, 8), 256, 0, stream>>>(AO, wouth, out_b, (float*)d_out,
                                                 nullptr, nullptr, nullptr);
}

// Round 9
// 160.191 us; speedup vs baseline: 1.3706x; 1.3706x over previous
//
#include <hip/hip_runtime.h>

typedef _Float16 f16;
typedef _Float16 f16x2 __attribute__((ext_vector_type(2)));
typedef _Float16 f16x4 __attribute__((ext_vector_type(4)));
typedef _Float16 f16x8 __attribute__((ext_vector_type(8)));
typedef float f32x4 __attribute__((ext_vector_type(4)));
typedef float f32x16 __attribute__((ext_vector_type(16)));

#define MFMA16(a, b, c) __builtin_amdgcn_mfma_f32_16x16x32_f16((a), (b), (c), 0, 0, 0)
#define MFMA32(a, b, c) __builtin_amdgcn_mfma_f32_32x32x16_f16((a), (b), (c), 0, 0, 0)

// ---------------- fp32 -> f16 convert ----------------
__global__ void cvt_f32_f16(const float* __restrict__ s, f16* __restrict__ d, int n) {
    int i = (blockIdx.x * 256 + threadIdx.x) * 4;
    if (i < n) {
        float4 v = *(const float4*)(s + i);
        f16x4 o = {(f16)v.x, (f16)v.y, (f16)v.z, (f16)v.w};
        *(f16x4*)(d + i) = o;
    }
}

// ---------------- NT GEMM: C[m][n] = sum_k A[m][k] * W[n][k] (+bias epilogues) ----
// MODE 0 epilogue packs K and V into MFMA-fragment-major layouts:
//   Kp[b][kb=s>>5][kc=d>>4][lane=(d>>3&1)*32+(s&31)][e=d&7]
//   Vp[b][db=d>>5][kw=s>>4][lane=(s>>3&1)*32+(d&31)][e=s&7]
template<int MODE>
__global__ __launch_bounds__(256) void gemm_nt(const f16* __restrict__ A, const f16* __restrict__ W,
                                               const float* __restrict__ bias, float* __restrict__ Cf,
                                               f16* __restrict__ Qb, f16* __restrict__ Kb,
                                               f16* __restrict__ Vt) {
    __shared__ f16 As[64][40];
    __shared__ f16 Bs[64][40];
    const int m0 = blockIdx.x * 64, n0 = blockIdx.y * 64;
    const int tid = threadIdx.x;
    const int w = tid >> 6, l = tid & 63;
    const int wm = w >> 1, wn = w & 1;
    const int lr = l & 15, lg = l >> 4;
    const int srow = tid >> 2, scol = (tid & 3) * 8;
    const f16* ag = A + (size_t)(m0 + srow) * 512 + scol;
    const f16* bg = W + (size_t)(n0 + srow) * 512 + scol;
    f32x4 acc[2][2] = {};
    f16x8 ar = *(const f16x8*)ag;
    f16x8 br = *(const f16x8*)bg;
    for (int k0 = 0; k0 < 512; k0 += 32) {
        *(f16x8*)&As[srow][scol] = ar;
        *(f16x8*)&Bs[srow][scol] = br;
        __syncthreads();
        if (k0 + 32 < 512) {
            ar = *(const f16x8*)(ag + k0 + 32);
            br = *(const f16x8*)(bg + k0 + 32);
        }
        f16x8 af[2], bf[2];
#pragma unroll
        for (int mf = 0; mf < 2; ++mf) af[mf] = *(f16x8*)&As[32 * wm + 16 * mf + lr][8 * lg];
#pragma unroll
        for (int nf = 0; nf < 2; ++nf) bf[nf] = *(f16x8*)&Bs[32 * wn + 16 * nf + lr][8 * lg];
#pragma unroll
        for (int mf = 0; mf < 2; ++mf)
#pragma unroll
            for (int nf = 0; nf < 2; ++nf) acc[mf][nf] = MFMA16(af[mf], bf[nf], acc[mf][nf]);
        __syncthreads();
    }
#pragma unroll
    for (int mf = 0; mf < 2; ++mf)
#pragma unroll
        for (int nf = 0; nf < 2; ++nf)
#pragma unroll
            for (int r = 0; r < 4; ++r) {
                int rr = 32 * wm + 16 * mf + 4 * lg + r;
                int cc = 32 * wn + 16 * nf + lr;
                int m = m0 + rr, e = n0 + cc;
                float val = acc[mf][nf][r] + bias[e];
                if (MODE == 0) {
                    int bb = m >> 11, s = m & 2047;
                    if (e < 512) {
                        Qb[((size_t)bb * 2048 + s) * 512 + e] = (f16)(val * 0.04419417382415922f);
                    } else if (e < 1024) {
                        int d = e - 512;
                        Kb[((((size_t)bb * 64 + (s >> 5)) * 32 + (d >> 4)) * 64
                            + ((d >> 3) & 1) * 32 + (s & 31)) * 8 + (d & 7)] = (f16)val;
                    } else {
                        int d = e - 1024;
                        Vt[((((size_t)bb * 16 + (d >> 5)) * 128 + (s >> 4)) * 64
                            + ((s >> 3) & 1) * 32 + (d & 31)) * 8 + (s & 7)] = (f16)val;
                    }
                } else {
                    Cf[(size_t)m * 512 + e] = val;
                }
            }
}

// ---------------- flash attention: 8 waves, QBLK=32, KEYTILE=256, 32x32 MFMA ----
// launch_bounds(512,3): 170 unified regs/wave -> no scratch spill (r7 spilled at 128).
// Wave j (0..7): QK^T computes S^T[32 keys (j-slice of 256)][32 q] = mfma(K, Q);
// softmax in-register; P via 16KB swizzled LDS; PV: wave owns O[32 q][64 d (j-slice)].
// K/V read from fragment-packed global layouts (lane-contiguous).
template<int NSPLIT, bool PART>
__global__ __launch_bounds__(512, 3) void flash_attn(const f16* __restrict__ Qb, const f16* __restrict__ Kb,
                                                     const f16* __restrict__ Vt, f16* __restrict__ AO,
                                                     f16* __restrict__ Opart, float* __restrict__ Ml) {
    __shared__ f16 Qs[32 * 512];   // [row][chunk^(row&7)] on 16B chunks
    __shared__ f16 P_lds[32 * 256];
    __shared__ float mbuf[32][8];
    __shared__ float lbuf[32][8];
    __shared__ float abuf[32];

    const int bid = blockIdx.x;
    const int xcd = bid & 7, slot = bid >> 3;
    const int b = xcd >> 1;
    const int t = slot * 2 + (xcd & 1);      // 0 .. 64*NSPLIT-1
    const int q0 = (t / NSPLIT) * 32;
    const int ks = t % NSPLIT;
    const int SPLITLEN = 2048 / NSPLIT;
    const int nkt = SPLITLEN / 256;

    const int tid = threadIdx.x;
    const int j = tid >> 6, l = tid & 63;
    const int q = l & 31, lh = l >> 5;

    const f16* Qg = Qb + ((size_t)b * 2048 + q0) * 512;
    const f16* Kg = Kb + ((size_t)b * 64 + (size_t)ks * (SPLITLEN / 32)) * 32 * 512;
    const f16* Vg = Vt + (size_t)b * 16 * 128 * 512 + (size_t)(ks * (SPLITLEN / 16)) * 512;

    // stage Q tile [32][512] into swizzled LDS (coalesced 16B per lane)
    for (int i = tid; i < 2048; i += 512) {
        int r = i >> 6, ch = i & 63;
        *(f16x8*)&Qs[r * 512 + ((ch ^ (r & 7)) * 8)] = *(const f16x8*)&Qg[(size_t)r * 512 + ch * 8];
    }

    f32x16 o[2] = {};
    float m_st = -1e30f, l_st = 0.f;
    char* Pq = (char*)&P_lds[0];
    const uint swz = ((uint)(q & 15)) << 4;
    const int qbase = q * 512, qx = q & 7;
    __syncthreads();

    for (int kt = 0; kt < nkt; ++kt) {
        const int key0 = kt * 256;
        // ---- QK^T (swapped): S^T[32 keys j-slice][32 q]; K frags lane-contiguous ----
        const f16* kp = Kg + ((size_t)((key0 >> 5) + j) * 32) * 512 + (size_t)l * 8;
        f32x16 sA = {}, sB = {};
#pragma unroll
        for (int kc = 0; kc < 32; kc += 2) {
            f16x8 k0 = *(const f16x8*)(kp + (size_t)kc * 512);
            f16x8 k1 = *(const f16x8*)(kp + (size_t)(kc + 1) * 512);
            f16x8 q0f = *(f16x8*)&Qs[qbase + (((2 * kc + lh) ^ qx) * 8)];
            f16x8 q1f = *(f16x8*)&Qs[qbase + (((2 * kc + 2 + lh) ^ qx) * 8)];
            sA = MFMA32(k0, q0f, sA);
            sB = MFMA32(k1, q1f, sB);
        }
        float s[16];
#pragma unroll
        for (int r = 0; r < 16; ++r) s[r] = sA[r] + sB[r];
        // ---- in-register partial max over own 32 keys ----
        float mt = s[0];
#pragma unroll
        for (int r = 1; r < 16; ++r) mt = fmaxf(mt, s[r]);
        mt = fmaxf(mt, __shfl_xor(mt, 32));
        if (l < 32) mbuf[q][j] = mt;
        __syncthreads();  // barrier 1
        float mnew = m_st;
        {
            float4 mv0 = *(float4*)&mbuf[q][0];
            float4 mv1 = *(float4*)&mbuf[q][4];
            mnew = fmaxf(mnew, fmaxf(fmaxf(mv0.x, mv0.y), fmaxf(mv0.z, mv0.w)));
            mnew = fmaxf(mnew, fmaxf(fmaxf(mv1.x, mv1.y), fmaxf(mv1.z, mv1.w)));
        }
        float alpha = __expf(m_st - mnew);
        if (l < 32) abuf[q] = alpha;
        float ps = 0.f;
#pragma unroll
        for (int r = 0; r < 16; ++r) {
            s[r] = __expf(s[r] - mnew);
            ps += s[r];
        }
        ps += __shfl_xor(ps, 32);
        if (l < 32) lbuf[q][j] = ps;
        // pack P -> P_lds[q][key], XOR-swizzled, f16x4 chunks (keys e+8i+4lh+32j)
        {
            const uint rowb = (uint)q * 512;
#pragma unroll
            for (int i = 0; i < 4; ++i) {
                int key = 8 * i + 4 * lh + 32 * j;
                f16x4 pk = {(f16)s[4 * i], (f16)s[4 * i + 1], (f16)s[4 * i + 2], (f16)s[4 * i + 3]};
                *(f16x4*)(Pq + ((rowb + (uint)key * 2) ^ swz)) = pk;
            }
        }
        m_st = mnew;
        __syncthreads();  // barrier 2
        // ---- combine l across 8 j-waves ----
        {
            float4 lv0 = *(float4*)&lbuf[q][0];
            float4 lv1 = *(float4*)&lbuf[q][4];
            l_st = l_st * alpha + ((lv0.x + lv0.y) + (lv0.z + lv0.w))
                                + ((lv1.x + lv1.y) + (lv1.z + lv1.w));
        }
        // ---- rescale O: alpha per O-reg's q-row via abuf broadcast ----
        float av[4][4];
#pragma unroll
        for (int g = 0; g < 4; ++g) {
            float4 a4 = *(float4*)&abuf[8 * g + 4 * lh];
            av[g][0] = a4.x; av[g][1] = a4.y; av[g][2] = a4.z; av[g][3] = a4.w;
        }
#pragma unroll
        for (int dt = 0; dt < 2; ++dt)
#pragma unroll
            for (int r = 0; r < 16; ++r) o[dt][r] *= av[r >> 2][r & 3];
        // ---- PV: O[32q][64d j-slice] += P[32q][256k] * V; V frags lane-contiguous ----
        const f16* vpb = Vg + ((size_t)(2 * j) * 128 + (key0 >> 4)) * 512 + (size_t)l * 8;
#pragma unroll
        for (int kk = 0; kk < 16; ++kk) {
            f16x8 paf = *(f16x8*)(Pq + (((uint)q * 512 + (uint)(16 * kk + 8 * lh) * 2) ^ swz));
#pragma unroll
            for (int dt = 0; dt < 2; ++dt) {
                f16x8 vf = *(const f16x8*)(vpb + ((size_t)dt * 128 + kk) * 512);
                o[dt] = MFMA32(paf, vf, o[dt]);
            }
        }
    }
    __syncthreads();  // protect abuf reuse below against stragglers in PV
    if (l < 32) abuf[q] = l_st;
    if (PART && l < 32 && j == 0) {
        Ml[((size_t)bid * 32 + q) * 2 + 0] = m_st;
        Ml[((size_t)bid * 32 + q) * 2 + 1] = l_st;
    }
    __syncthreads();
    float iv[4][4];
#pragma unroll
    for (int g = 0; g < 4; ++g) {
        float4 a4 = *(float4*)&abuf[8 * g + 4 * lh];
        iv[g][0] = 1.f / a4.x; iv[g][1] = 1.f / a4.y; iv[g][2] = 1.f / a4.z; iv[g][3] = 1.f / a4.w;
    }
    f16* op = PART ? (Opart + (size_t)bid * 32 * 512 + 64 * j)
                   : (AO + ((size_t)(b * 2048 + q0)) * 512 + 64 * j);
#pragma unroll
    for (int r = 0; r < 16; ++r) {
        int qr = (r & 3) + 8 * (r >> 2) + 4 * lh;
        float inv = iv[r >> 2][r & 3];
#pragma unroll
        for (int dt = 0; dt < 2; ++dt)
            op[(size_t)qr * 512 + 32 * dt + q] = (f16)(o[dt][r] * inv);
    }
}

// ---------------- split-K combine (NS partials per 32-row q-block) ----------------
template<int NS>
__global__ __launch_bounds__(256) void combineN(const f16* __restrict__ Opart, const float* __restrict__ Ml,
                                                f16* __restrict__ AO) {
    int gid = blockIdx.x * 256 + threadIdx.x;
    int row = gid >> 6, col0 = (gid & 63) * 8;
    int b = row >> 11, qq = row & 2047;
    int qb = qq >> 5, qr = qq & 31;
    int bids[NS];
    float m[NS], ll[NS];
#pragma unroll
    for (int s = 0; s < NS; ++s) {
        int t = qb * NS + s;
        bids[s] = (t >> 1) * 8 + 2 * b + (t & 1);
        m[s] = Ml[((size_t)bids[s] * 32 + qr) * 2];
        ll[s] = Ml[((size_t)bids[s] * 32 + qr) * 2 + 1];
    }
    float M = m[0];
#pragma unroll
    for (int s = 1; s < NS; ++s) M = fmaxf(M, m[s]);
    float c[NS], W = 0.f;
#pragma unroll
    for (int s = 0; s < NS; ++s) {
        c[s] = __expf(m[s] - M) * ll[s];
        W += c[s];
    }
    float invW = 1.f / W;
    float av[8] = {};
#pragma unroll
    for (int s = 0; s < NS; ++s) {
        f16x8 v = *(const f16x8*)&Opart[((size_t)bids[s] * 32 + qr) * 512 + col0];
        float cs = c[s] * invW;
#pragma unroll
        for (int jj = 0; jj < 8; ++jj) av[jj] += cs * (float)v[jj];
    }
    f16x8 o8;
#pragma unroll
    for (int jj = 0; jj < 8; ++jj) o8[jj] = (f16)av[jj];
    *(f16x8*)&AO[(size_t)row * 512 + col0] = o8;
}

// ---------------- launch ----------------
extern "C" void kernel_launch(void* const* d_in, const int* in_sizes, int n_in,
                              void* d_out, int out_size, void* d_ws, size_t ws_size,
                              hipStream_t stream) {
    (void)in_sizes; (void)n_in; (void)out_size;
    const float* x = (const float*)d_in[0];
    const float* qkv_w = (const float*)d_in[1];
    const float* qkv_b = (const float*)d_in[2];
    const float* out_w = (const float*)d_in[3];
    const float* out_b = (const float*)d_in[4];
    char* ws = (char*)d_ws;
    f16* xh    = (f16*)(ws + 0);
    f16* wqkvh = (f16*)(ws + 8388608);
    f16* wouth = (f16*)(ws + 9961472);
    f16* Qb    = (f16*)(ws + 10485760);
    f16* Kb    = (f16*)(ws + 18874368);  // packed K fragments, 8,388,608
    f16* Vt    = (f16*)(ws + 27262976);  // packed V fragments, 8,388,608
    f16* AO    = (f16*)(ws + 35651584);
    f16* Opart = (f16*)(ws + 44040192);               // 512*32*512*2 = 16,777,216
    float* Ml  = (float*)(ws + 44040192 + 16777216);  // 512*32*2*4 = 131,072
    const size_t NEED = 44040192ull + 16777216ull + 131072ull;

    cvt_f32_f16<<<4096, 256, 0, stream>>>(x, xh, 4194304);
    cvt_f32_f16<<<768, 256, 0, stream>>>(qkv_w, wqkvh, 786432);
    cvt_f32_f16<<<256, 256, 0, stream>>>(out_w, wouth, 262144);

    gemm_nt<0><<<dim3(128, 24), 256, 0, stream>>>(xh, wqkvh, qkv_b, nullptr, Qb, Kb, Vt);

    if (ws_size >= NEED) {
        flash_attn<2, true><<<512, 512, 0, stream>>>(Qb, Kb, Vt, nullptr, Opart, Ml);
        combineN<2><<<2048, 256, 0, stream>>>(Opart, Ml, AO);
    } else {
        flash_attn<1, false><<<256, 512, 0, stream>>>(Qb, Kb, Vt, AO, nullptr, nullptr);
    }

    gemm_nt<1><<<dim3(128, 8), 256, 0, stream>>>(AO, wouth, out_b, (float*)d_out,
                                                 nullptr, nullptr, nullptr);
}

// Round 10
// 118.713 us; speedup vs baseline: 1.8495x; 1.3494x over previous
//
#include <hip/hip_runtime.h>

typedef _Float16 f16;
typedef _Float16 f16x2 __attribute__((ext_vector_type(2)));
typedef _Float16 f16x4 __attribute__((ext_vector_type(4)));
typedef _Float16 f16x8 __attribute__((ext_vector_type(8)));
typedef float f32x4 __attribute__((ext_vector_type(4)));
typedef float f32x16 __attribute__((ext_vector_type(16)));

#define MFMA16(a, b, c) __builtin_amdgcn_mfma_f32_16x16x32_f16((a), (b), (c), 0, 0, 0)
#define MFMA32(a, b, c) __builtin_amdgcn_mfma_f32_32x32x16_f16((a), (b), (c), 0, 0, 0)

// ---------------- fp32 -> f16 convert ----------------
__global__ void cvt_f32_f16(const float* __restrict__ s, f16* __restrict__ d, int n) {
    int i = (blockIdx.x * 256 + threadIdx.x) * 4;
    if (i < n) {
        float4 v = *(const float4*)(s + i);
        f16x4 o = {(f16)v.x, (f16)v.y, (f16)v.z, (f16)v.w};
        *(f16x4*)(d + i) = o;
    }
}

// ---------------- NT GEMM, 128x128 tile, BK=32, double-buffered LDS ----------------
// 4 waves, wave (wm,wn) owns 64x64 quadrant = 4x4 16x16 frags. One barrier/K-step.
// MODE 0 epilogue packs K and V into MFMA-fragment-major layouts:
//   Kp[b][kb=s>>5][kc=d>>4][lane=(d>>3&1)*32+(s&31)][e=d&7]
//   Vp[b][db=d>>5][kw=s>>4][lane=(s>>3&1)*32+(d&31)][e=s&7]
template<int MODE>
__global__ __launch_bounds__(256, 3) void gemm_nt(const f16* __restrict__ A, const f16* __restrict__ W,
                                                  const float* __restrict__ bias, float* __restrict__ Cf,
                                                  f16* __restrict__ Qb, f16* __restrict__ Kb,
                                                  f16* __restrict__ Vt) {
    __shared__ f16 As[2][128][40];  // 32 + 8 pad
    __shared__ f16 Bs[2][128][40];
    const int m0 = blockIdx.x * 128, n0 = blockIdx.y * 128;
    const int tid = threadIdx.x;
    const int w = tid >> 6, l = tid & 63;
    const int wm = w >> 1, wn = w & 1;
    const int lr = l & 15, lg = l >> 4;
    const int srow = tid >> 1;              // staging row 0..127
    const int scol = (tid & 1) * 16;        // staging col 0 or 16
    const f16* ag = A + (size_t)(m0 + srow) * 512 + scol;
    const f16* bg = W + (size_t)(n0 + srow) * 512 + scol;
    f32x4 acc[4][4] = {};
    // prologue: stage k0=0 into buf 0
    {
        f16x8 a0 = *(const f16x8*)(ag + 0), a1 = *(const f16x8*)(ag + 8);
        f16x8 b0 = *(const f16x8*)(bg + 0), b1 = *(const f16x8*)(bg + 8);
        *(f16x8*)&As[0][srow][scol] = a0;
        *(f16x8*)&As[0][srow][scol + 8] = a1;
        *(f16x8*)&Bs[0][srow][scol] = b0;
        *(f16x8*)&Bs[0][srow][scol + 8] = b1;
    }
    __syncthreads();
    int cur = 0;
    for (int k0 = 0; k0 < 512; k0 += 32) {
        f16x8 na0, na1, nb0, nb1;
        const bool more = (k0 + 32 < 512);
        if (more) {
            na0 = *(const f16x8*)(ag + k0 + 32);
            na1 = *(const f16x8*)(ag + k0 + 40);
            nb0 = *(const f16x8*)(bg + k0 + 32);
            nb1 = *(const f16x8*)(bg + k0 + 40);
        }
        f16x8 af[4], bf[4];
#pragma unroll
        for (int i = 0; i < 4; ++i) af[i] = *(f16x8*)&As[cur][64 * wm + 16 * i + lr][8 * lg];
#pragma unroll
        for (int i = 0; i < 4; ++i) bf[i] = *(f16x8*)&Bs[cur][64 * wn + 16 * i + lr][8 * lg];
#pragma unroll
        for (int mf = 0; mf < 4; ++mf)
#pragma unroll
            for (int nf = 0; nf < 4; ++nf) acc[mf][nf] = MFMA16(af[mf], bf[nf], acc[mf][nf]);
        if (more) {
            *(f16x8*)&As[cur ^ 1][srow][scol] = na0;
            *(f16x8*)&As[cur ^ 1][srow][scol + 8] = na1;
            *(f16x8*)&Bs[cur ^ 1][srow][scol] = nb0;
            *(f16x8*)&Bs[cur ^ 1][srow][scol + 8] = nb1;
            __syncthreads();
            cur ^= 1;
        }
    }
#pragma unroll
    for (int mf = 0; mf < 4; ++mf)
#pragma unroll
        for (int nf = 0; nf < 4; ++nf)
#pragma unroll
            for (int r = 0; r < 4; ++r) {
                int rr = 64 * wm + 16 * mf + 4 * lg + r;
                int cc = 64 * wn + 16 * nf + lr;
                int m = m0 + rr, e = n0 + cc;
                float val = acc[mf][nf][r] + bias[e];
                if (MODE == 0) {
                    int bb = m >> 11, s = m & 2047;
                    if (e < 512) {
                        Qb[((size_t)bb * 2048 + s) * 512 + e] = (f16)(val * 0.04419417382415922f);
                    } else if (e < 1024) {
                        int d = e - 512;
                        Kb[((((size_t)bb * 64 + (s >> 5)) * 32 + (d >> 4)) * 64
                            + ((d >> 3) & 1) * 32 + (s & 31)) * 8 + (d & 7)] = (f16)val;
                    } else {
                        int d = e - 1024;
                        Vt[((((size_t)bb * 16 + (d >> 5)) * 128 + (s >> 4)) * 64
                            + ((s >> 3) & 1) * 32 + (d & 31)) * 8 + (s & 7)] = (f16)val;
                    }
                } else {
                    Cf[(size_t)m * 512 + e] = val;
                }
            }
}

// ---------------- flash attention: 8 waves, QBLK=32, KEYTILE=256, 32x32 MFMA ----
// launch_bounds(512,2): 256 unified regs (1 WG/CU either way at 8 waves).
// Rotating register prefetch: K depth-8 ring through QK^T; V pairs preloaded at
// kt top (hidden under QK^T+softmax), depth-4-pair ring through PV.
template<int NSPLIT, bool PART>
__global__ __launch_bounds__(512, 2) void flash_attn(const f16* __restrict__ Qb, const f16* __restrict__ Kb,
                                                     const f16* __restrict__ Vt, f16* __restrict__ AO,
                                                     f16* __restrict__ Opart, float* __restrict__ Ml) {
    __shared__ f16 Qs[32 * 512];   // [row][chunk^(row&7)] on 16B chunks
    __shared__ f16 P_lds[32 * 256];
    __shared__ float mbuf[32][8];
    __shared__ float lbuf[32][8];
    __shared__ float abuf[32];

    const int bid = blockIdx.x;
    const int xcd = bid & 7, slot = bid >> 3;
    const int b = xcd >> 1;
    const int t = slot * 2 + (xcd & 1);      // 0 .. 64*NSPLIT-1
    const int q0 = (t / NSPLIT) * 32;
    const int ks = t % NSPLIT;
    const int SPLITLEN = 2048 / NSPLIT;
    const int nkt = SPLITLEN / 256;

    const int tid = threadIdx.x;
    const int j = tid >> 6, l = tid & 63;
    const int q = l & 31, lh = l >> 5;

    const f16* Qg = Qb + ((size_t)b * 2048 + q0) * 512;
    const f16* Kg = Kb + ((size_t)b * 64 + (size_t)ks * (SPLITLEN / 32)) * 32 * 512;
    const f16* Vg = Vt + (size_t)b * 16 * 128 * 512 + (size_t)(ks * (SPLITLEN / 16)) * 512;

    // stage Q tile [32][512] into swizzled LDS (coalesced 16B per lane)
    for (int i = tid; i < 2048; i += 512) {
        int r = i >> 6, ch = i & 63;
        *(f16x8*)&Qs[r * 512 + ((ch ^ (r & 7)) * 8)] = *(const f16x8*)&Qg[(size_t)r * 512 + ch * 8];
    }

    f32x16 o[2] = {};
    float m_st = -1e30f, l_st = 0.f;
    char* Pq = (char*)&P_lds[0];
    const uint swz = ((uint)(q & 15)) << 4;
    const int qbase = q * 512, qx = q & 7;
    __syncthreads();

    for (int kt = 0; kt < nkt; ++kt) {
        const int key0 = kt * 256;
        const f16* kp = Kg + ((size_t)((key0 >> 5) + j) * 32) * 512 + (size_t)l * 8;
        const f16* vpb = Vg + ((size_t)(2 * j) * 128 + (key0 >> 4)) * 512 + (size_t)l * 8;
        // ---- batch preload: K ring (8) + V pairs for kk=0..3 (8) ----
        f16x8 kr[8], vr[8];
#pragma unroll
        for (int i = 0; i < 8; ++i) kr[i] = *(const f16x8*)(kp + (size_t)i * 512);
#pragma unroll
        for (int i = 0; i < 4; ++i) {
            vr[2 * i] = *(const f16x8*)(vpb + (size_t)i * 512);
            vr[2 * i + 1] = *(const f16x8*)(vpb + (size_t)(128 + i) * 512);
        }
        // ---- QK^T (swapped): S^T[32 keys j-slice][32 q]; K ring prefetch ----
        f32x16 sA = {}, sB = {};
#pragma unroll
        for (int kc = 0; kc < 32; kc += 2) {
            f16x8 k0 = kr[kc & 7];
            f16x8 k1 = kr[(kc & 7) + 1];
            if (kc < 24) {
                kr[kc & 7] = *(const f16x8*)(kp + (size_t)(kc + 8) * 512);
                kr[(kc & 7) + 1] = *(const f16x8*)(kp + (size_t)(kc + 9) * 512);
            }
            f16x8 q0f = *(f16x8*)&Qs[qbase + (((2 * kc + lh) ^ qx) * 8)];
            f16x8 q1f = *(f16x8*)&Qs[qbase + (((2 * kc + 2 + lh) ^ qx) * 8)];
            sA = MFMA32(k0, q0f, sA);
            sB = MFMA32(k1, q1f, sB);
        }
        float s[16];
#pragma unroll
        for (int r = 0; r < 16; ++r) s[r] = sA[r] + sB[r];
        // ---- in-register partial max over own 32 keys ----
        float mt = s[0];
#pragma unroll
        for (int r = 1; r < 16; ++r) mt = fmaxf(mt, s[r]);
        mt = fmaxf(mt, __shfl_xor(mt, 32));
        if (l < 32) mbuf[q][j] = mt;
        __syncthreads();  // barrier 1
        float mnew = m_st;
        {
            float4 mv0 = *(float4*)&mbuf[q][0];
            float4 mv1 = *(float4*)&mbuf[q][4];
            mnew = fmaxf(mnew, fmaxf(fmaxf(mv0.x, mv0.y), fmaxf(mv0.z, mv0.w)));
            mnew = fmaxf(mnew, fmaxf(fmaxf(mv1.x, mv1.y), fmaxf(mv1.z, mv1.w)));
        }
        float alpha = __expf(m_st - mnew);
        if (l < 32) abuf[q] = alpha;
        float ps = 0.f;
#pragma unroll
        for (int r = 0; r < 16; ++r) {
            s[r] = __expf(s[r] - mnew);
            ps += s[r];
        }
        ps += __shfl_xor(ps, 32);
        if (l < 32) lbuf[q][j] = ps;
        // pack P -> P_lds[q][key], XOR-swizzled, f16x4 chunks (keys e+8i+4lh+32j)
        {
            const uint rowb = (uint)q * 512;
#pragma unroll
            for (int i = 0; i < 4; ++i) {
                int key = 8 * i + 4 * lh + 32 * j;
                f16x4 pk = {(f16)s[4 * i], (f16)s[4 * i + 1], (f16)s[4 * i + 2], (f16)s[4 * i + 3]};
                *(f16x4*)(Pq + ((rowb + (uint)key * 2) ^ swz)) = pk;
            }
        }
        m_st = mnew;
        __syncthreads();  // barrier 2
        // ---- combine l across 8 j-waves ----
        {
            float4 lv0 = *(float4*)&lbuf[q][0];
            float4 lv1 = *(float4*)&lbuf[q][4];
            l_st = l_st * alpha + ((lv0.x + lv0.y) + (lv0.z + lv0.w))
                                + ((lv1.x + lv1.y) + (lv1.z + lv1.w));
        }
        // ---- rescale O: alpha per O-reg's q-row via abuf broadcast ----
        float av[4][4];
#pragma unroll
        for (int g = 0; g < 4; ++g) {
            float4 a4 = *(float4*)&abuf[8 * g + 4 * lh];
            av[g][0] = a4.x; av[g][1] = a4.y; av[g][2] = a4.z; av[g][3] = a4.w;
        }
#pragma unroll
        for (int dt = 0; dt < 2; ++dt)
#pragma unroll
            for (int r = 0; r < 16; ++r) o[dt][r] *= av[r >> 2][r & 3];
        // ---- PV: O[32q][64d j-slice] += P[32q][256k] * V; V ring prefetch ----
#pragma unroll
        for (int kk = 0; kk < 16; ++kk) {
            f16x8 v0 = vr[(kk & 3) * 2];
            f16x8 v1 = vr[(kk & 3) * 2 + 1];
            if (kk < 12) {
                vr[(kk & 3) * 2] = *(const f16x8*)(vpb + (size_t)(kk + 4) * 512);
                vr[(kk & 3) * 2 + 1] = *(const f16x8*)(vpb + (size_t)(128 + kk + 4) * 512);
            }
            f16x8 paf = *(f16x8*)(Pq + (((uint)q * 512 + (uint)(16 * kk + 8 * lh) * 2) ^ swz));
            o[0] = MFMA32(paf, v0, o[0]);
            o[1] = MFMA32(paf, v1, o[1]);
        }
    }
    __syncthreads();  // protect abuf reuse below against stragglers in PV
    if (l < 32) abuf[q] = l_st;
    if (PART && l < 32 && j == 0) {
        Ml[((size_t)bid * 32 + q) * 2 + 0] = m_st;
        Ml[((size_t)bid * 32 + q) * 2 + 1] = l_st;
    }
    __syncthreads();
    float iv[4][4];
#pragma unroll
    for (int g = 0; g < 4; ++g) {
        float4 a4 = *(float4*)&abuf[8 * g + 4 * lh];
        iv[g][0] = 1.f / a4.x; iv[g][1] = 1.f / a4.y; iv[g][2] = 1.f / a4.z; iv[g][3] = 1.f / a4.w;
    }
    f16* op = PART ? (Opart + (size_t)bid * 32 * 512 + 64 * j)
                   : (AO + ((size_t)(b * 2048 + q0)) * 512 + 64 * j);
#pragma unroll
    for (int r = 0; r < 16; ++r) {
        int qr = (r & 3) + 8 * (r >> 2) + 4 * lh;
        float inv = iv[r >> 2][r & 3];
#pragma unroll
        for (int dt = 0; dt < 2; ++dt)
            op[(size_t)qr * 512 + 32 * dt + q] = (f16)(o[dt][r] * inv);
    }
}

// ---------------- split-K combine (NS partials per 32-row q-block) ----------------
template<int NS>
__global__ __launch_bounds__(256) void combineN(const f16* __restrict__ Opart, const float* __restrict__ Ml,
                                                f16* __restrict__ AO) {
    int gid = blockIdx.x * 256 + threadIdx.x;
    int row = gid >> 6, col0 = (gid & 63) * 8;
    int b = row >> 11, qq = row & 2047;
    int qb = qq >> 5, qr = qq & 31;
    int bids[NS];
    float m[NS], ll[NS];
#pragma unroll
    for (int s = 0; s < NS; ++s) {
        int t = qb * NS + s;
        bids[s] = (t >> 1) * 8 + 2 * b + (t & 1);
        m[s] = Ml[((size_t)bids[s] * 32 + qr) * 2];
        ll[s] = Ml[((size_t)bids[s] * 32 + qr) * 2 + 1];
    }
    float M = m[0];
#pragma unroll
    for (int s = 1; s < NS; ++s) M = fmaxf(M, m[s]);
    float c[NS], W = 0.f;
#pragma unroll
    for (int s = 0; s < NS; ++s) {
        c[s] = __expf(m[s] - M) * ll[s];
        W += c[s];
    }
    float invW = 1.f / W;
    float av[8] = {};
#pragma unroll
    for (int s = 0; s < NS; ++s) {
        f16x8 v = *(const f16x8*)&Opart[((size_t)bids[s] * 32 + qr) * 512 + col0];
        float cs = c[s] * invW;
#pragma unroll
        for (int jj = 0; jj < 8; ++jj) av[jj] += cs * (float)v[jj];
    }
    f16x8 o8;
#pragma unroll
    for (int jj = 0; jj < 8; ++jj) o8[jj] = (f16)av[jj];
    *(f16x8*)&AO[(size_t)row * 512 + col0] = o8;
}

// ---------------- launch ----------------
extern "C" void kernel_launch(void* const* d_in, const int* in_sizes, int n_in,
                              void* d_out, int out_size, void* d_ws, size_t ws_size,
                              hipStream_t stream) {
    (void)in_sizes; (void)n_in; (void)out_size;
    const float* x = (const float*)d_in[0];
    const float* qkv_w = (const float*)d_in[1];
    const float* qkv_b = (const float*)d_in[2];
    const float* out_w = (const float*)d_in[3];
    const float* out_b = (const float*)d_in[4];
    char* ws = (char*)d_ws;
    f16* xh    = (f16*)(ws + 0);
    f16* wqkvh = (f16*)(ws + 8388608);
    f16* wouth = (f16*)(ws + 9961472);
    f16* Qb    = (f16*)(ws + 10485760);
    f16* Kb    = (f16*)(ws + 18874368);  // packed K fragments, 8,388,608
    f16* Vt    = (f16*)(ws + 27262976);  // packed V fragments, 8,388,608
    f16* AO    = (f16*)(ws + 35651584);
    f16* Opart = (f16*)(ws + 44040192);               // 512*32*512*2 = 16,777,216
    float* Ml  = (float*)(ws + 44040192 + 16777216);  // 512*32*2*4 = 131,072
    const size_t NEED = 44040192ull + 16777216ull + 131072ull;

    cvt_f32_f16<<<4096, 256, 0, stream>>>(x, xh, 4194304);
    cvt_f32_f16<<<768, 256, 0, stream>>>(qkv_w, wqkvh, 786432);
    cvt_f32_f16<<<256, 256, 0, stream>>>(out_w, wouth, 262144);

    gemm_nt<0><<<dim3(64, 12), 256, 0, stream>>>(xh, wqkvh, qkv_b, nullptr, Qb, Kb, Vt);

    if (ws_size >= NEED) {
        flash_attn<2, true><<<512, 512, 0, stream>>>(Qb, Kb, Vt, nullptr, Opart, Ml);
        combineN<2><<<2048, 256, 0, stream>>>(Opart, Ml, AO);
    } else {
        flash_attn<1, false><<<256, 512, 0, stream>>>(Qb, Kb, Vt, AO, nullptr, nullptr);
    }

    gemm_nt<1><<<dim3(64, 4), 256, 0, stream>>>(AO, wouth, out_b, (float*)d_out,
                                                nullptr, nullptr, nullptr);
}